// Round 14
// baseline (309.706 us; speedup 1.0000x reference)
//
#include <hip/hip_runtime.h>
#include <math.h>

#define NN 20000
#define EE 640000
#define NB4C 5000
#define NCH 80          // edge chunks per graph
#define CHE 8000        // edges per chunk (NCH*CHE == EE)

typedef unsigned short ushortT;
typedef unsigned int uintT;

__device__ __forceinline__ float lrelu(float x){ return x >= 0.f ? x : 0.2f*x; }
__device__ __forceinline__ ushortT f2bf(float x){
  uintT u = __float_as_uint(x);
  u = (u + 0x7FFFu + ((u >> 16) & 1u)) >> 16;   // RNE
  return (ushortT)u;
}
__device__ __forceinline__ float bfl(uintT w){ return __uint_as_float(w << 16); }
__device__ __forceinline__ float bfh(uintT w){ return __uint_as_float(w & 0xFFFF0000u); }

// ---------------- fused: metadata GEMV+pack (P, 22048 floats)  UNION  LDS histogram
// P layout: W1@0(128) B1@128 AL1@256 AR1@384 / W2@512 B2@4608 AL2@4640 AR2@4672
// W3@4704 B3@8800 AL3@8928 AR3@9056 / W4@9184 B4@13280 AL4@13312 AR4@13344
// W5@13376 B5@17472 AL5@17600 AR5@17728 / W6@17856 B6@21952 AL6@21984 AR6@22016
__global__ __launch_bounds__(256) void k_prmhist(const float* __restrict__ m1,
        const float* __restrict__ mt, const float* __restrict__ Whin,
        const float* __restrict__ bhin, const float* __restrict__ Whout,
        const float* __restrict__ bhout, float* __restrict__ P,
        const int* __restrict__ dst_in, const int* __restrict__ dst_trg,
        int* __restrict__ histB){
  __shared__ int hist[NN/2];
  int b = blockIdx.x;
  if (b < 2*NCH){
    int g = b / NCH, c = b % NCH;
    const int* dst = g ? dst_trg : dst_in;
    for (int i=threadIdx.x; i<NN/2; i+=256) hist[i] = 0;
    __syncthreads();
    int e0 = c*CHE;
    for (int k=threadIdx.x; k<CHE; k+=256){
      int d = dst[e0+k];
      atomicAdd(&hist[d>>1], (d&1) ? 65536 : 1);
    }
    __syncthreads();
    int* outp = histB + b*(NN/2);
    for (int i=threadIdx.x; i<NN/2; i+=256) outp[i] = hist[i];
    return;
  }
  int t = (b - 2*NCH)*256 + threadIdx.x;
  if (t >= 22048) return;
  int sj; bool inA;
  if      (t < 128)  { sj = 256+t;          inA=true; }
  else if (t < 256)  { sj = 384+(t-128);    inA=true; }
  else if (t < 384)  { sj = t-256;          inA=true; }
  else if (t < 512)  { sj = 128+(t-384);    inA=true; }
  else if (t < 4608) { sj = 576+(t-512);    inA=true; }
  else if (t < 4640) { sj = 4672+(t-4608);  inA=true; }
  else if (t < 4672) { sj = 512+(t-4640);   inA=true; }
  else if (t < 4704) { sj = 544+(t-4672);   inA=true; }
  else { inA=false;
    if      (t < 8800)  { int k=t-4704, o=k>>5, i=k&31; sj = 768 + (o>>5)*3072+(o&31)*32+i; }
    else if (t < 8928)  { int o=t-8800; sj = 13056 + (o>>5)*96+(o&31); }
    else if (t < 9056)  { int q=t-8928;       sj = (q>>6)*192+(q&63); }
    else if (t < 9184)  { int q=(t-9056)+128; sj = (q>>6)*192+(q&63); }
    else if (t < 13280) { sj = 13632 + (t-9184); }
    else if (t < 13312) { sj = 25920 + (t-13280); }
    else if (t < 13344) { sj = 13440 + (t-13312); }
    else if (t < 13376) { sj = 13472 + (t-13344); }
    else if (t < 17472) { int k=t-13376, o=k>>5, i=k&31; sj = 768 + (o>>5)*3072+(32+(o&31))*32+i; }
    else if (t < 17600) { int o=t-17472; sj = 13056 + (o>>5)*96+32+(o&31); }
    else if (t < 17728) { int q=t-17600;       sj = (q>>6)*192+64+(q&63); }
    else if (t < 17856) { int q=(t-17728)+128; sj = (q>>6)*192+64+(q&63); }
    else if (t < 21952) { sj = 13632+4096+(t-17856); }
    else if (t < 21984) { sj = 25920+32+(t-21952); }
    else if (t < 22016) { sj = 13440+64+(t-21984); }
    else                { sj = 13440+96+(t-22016); }
  }
  float acc;
  if (inA){
    acc = bhin[sj];
    #pragma unroll 8
    for (int k=0;k<64;++k) acc = fmaf(m1[k], Whin[k*4704 + sj], acc);
  } else {
    acc = bhout[sj];
    #pragma unroll 8
    for (int k=0;k<64;++k) acc = fmaf(mt[k], Whout[k*26016 + sj], acc);
  }
  P[t] = acc;
}

// ---- 2-level scan of per-node totals (fold of 80 chunk planes) -> off
__global__ __launch_bounds__(1024) void k_csrA(const int* __restrict__ histB,
        int* __restrict__ exc, int* __restrict__ bsum){
  int b = blockIdx.x, t = threadIdx.x;      // 40 blocks
  int g = b/20, c2 = b%20;
  int i = c2*1024 + t;
  int tot = 0;
  if (i < NN){
    int sh = (i&1)*16;
    for (int cb=0; cb<NCH; ++cb){
      int w = histB[(g*NCH+cb)*(NN/2) + (i>>1)];
      tot += (w >> sh) & 0xFFFF;
    }
  }
  __shared__ int s[1024];
  s[t] = tot;
  __syncthreads();
  for (int d=1; d<1024; d<<=1){
    int v = (t>=d) ? s[t-d] : 0;
    __syncthreads();
    s[t] += v;
    __syncthreads();
  }
  exc[b*1024 + t] = s[t] - tot;
  if (t == 1023) bsum[b] = s[t];
}

// serial fold of 40 block sums + P2 dots + off[NN]
__global__ void k_csrB(const int* __restrict__ bsum, int* __restrict__ bbase,
        int* __restrict__ off_in, int* __restrict__ off_trg,
        const float* __restrict__ P, float* __restrict__ P2){
  int t = threadIdx.x;
  if (t < 8){
    int hh = t >> 1, sel = t & 1;
    const float* W = P;
    const float* A = P + 256 + sel*128;
    float c = 0.f;
    #pragma unroll 8
    for (int d=0; d<32; ++d) c = fmaf(W[hh*32+d], A[hh*32+d], c);
    P2[sel*4 + hh] = c;
  } else if (t == 8){
    int base = 0;
    for (int b=0; b<20; ++b){ bbase[b] = base; base += bsum[b]; }
  } else if (t == 9){
    int base = 0;
    for (int b=20; b<40; ++b){ bbase[b] = base; base += bsum[b]; }
  } else if (t == 10) off_in[NN]  = EE;
  else if   (t == 11) off_trg[NN] = EE;
}

// merged: off[i] write + per-chunk running prefix -> bases[g][chunk][node]
__global__ __launch_bounds__(1024) void k_csrC(const int* __restrict__ histB,
        const int* __restrict__ exc, const int* __restrict__ bbase,
        int* __restrict__ off_in, int* __restrict__ off_trg,
        int* __restrict__ bases){
  int b = blockIdx.x, t = threadIdx.x;      // 40 blocks
  int g = b/20, c2 = b%20;
  int i = c2*1024 + t;
  if (i >= NN) return;
  int* off = g ? off_trg : off_in;
  int running = exc[b*1024 + t] + bbase[b];
  off[i] = running;
  int sh = (i&1)*16;
  for (int cb=0; cb<NCH; ++cb){
    bases[(g*NCH+cb)*NN + i] = running;
    int w = histB[(g*NCH+cb)*(NN/2) + (i>>1)];
    running += (w >> sh) & 0xFFFF;
  }
}

// fill: block = (graph, node-half, chunk); LDS bump allocator (no global atomic returns)
__global__ __launch_bounds__(256) void k_fillL(const int* __restrict__ src_in,
        const int* __restrict__ dst_in, const int* __restrict__ src_trg,
        const int* __restrict__ dst_trg, const int* __restrict__ bases,
        ushortT* __restrict__ csr_in, ushortT* __restrict__ csr_trg){
  int b = blockIdx.x;                  // 0..319
  int g = b / (2*NCH);
  int rem = b % (2*NCH);
  int half = rem / NCH, c = rem % NCH;
  const int* src = g ? src_trg : src_in;
  const int* dst = g ? dst_trg : dst_in;
  ushortT* csr = g ? csr_trg : csr_in;
  __shared__ int alloc[NN/2];
  const int* basep = bases + (g*NCH+c)*NN + half*(NN/2);
  for (int i=threadIdx.x; i<NN/2; i+=256) alloc[i] = basep[i];
  __syncthreads();
  int e0 = c*CHE;
  int lo = half*(NN/2);
  for (int k=threadIdx.x; k<CHE; k+=256){
    int d = dst[e0+k];
    int dl = d - lo;
    if ((unsigned)dl < (unsigned)(NN/2)){
      int p = atomicAdd(&alloc[dl], 1);
      csr[p] = (ushortT)src[e0+k];
    }
  }
}

// ---------------- fused feat+el/er; feat stored BF16 INTERLEAVED [n][OUT],
// el/er stored [n][H] (H=1 -> [n]).
template<int IN, int OUT, int H>
__global__ __launch_bounds__(256) void k_featel(const float* __restrict__ z,
        const float* __restrict__ W, const float* __restrict__ AL,
        const float* __restrict__ AR, ushortT* __restrict__ featb,
        float* __restrict__ el, float* __restrict__ er){
  __shared__ float Ws[IN*(OUT+1)];
  __shared__ float ALs[OUT], ARs[OUT];
  for (int idx=threadIdx.x; idx<IN*OUT; idx+=256){
    int o = idx / IN, i = idx % IN;
    Ws[i*(OUT+1) + o] = W[idx];
  }
  for (int idx=threadIdx.x; idx<OUT; idx+=256){ ALs[idx]=AL[idx]; ARs[idx]=AR[idx]; }
  __syncthreads();
  int tid = blockIdx.x*256 + threadIdx.x;
  int n = tid / OUT, o = tid % OUT;
  const float4* z4 = (const float4*)(z + n*IN);
  float acc = 0.f;
  #pragma unroll
  for (int i=0;i<IN/4;++i){
    float4 zv = z4[i];
    acc = fmaf(zv.x, Ws[(4*i+0)*(OUT+1)+o], acc);
    acc = fmaf(zv.y, Ws[(4*i+1)*(OUT+1)+o], acc);
    acc = fmaf(zv.z, Ws[(4*i+2)*(OUT+1)+o], acc);
    acc = fmaf(zv.w, Ws[(4*i+3)*(OUT+1)+o], acc);
  }
  featb[n*OUT + o] = f2bf(acc);
  float a = acc * ALs[o], b = acc * ARs[o];
  #pragma unroll
  for (int msk=1; msk<32; msk<<=1){
    a += __shfl_xor(a, msk);
    b += __shfl_xor(b, msk);
  }
  if ((o & 31) == 0){
    int h = o >> 5;
    el[n*H + h] = a;
    er[n*H + h] = b;
  }
}

// ---------------- layer 1 fused (IN=1 algebraic collapse) — f32 path, unchanged
__global__ __launch_bounds__(256) void k_l1(const int* __restrict__ off,
        const ushortT* __restrict__ csr, const float* __restrict__ X,
        const float* __restrict__ P, const float* __restrict__ P2,
        float* __restrict__ out){
  int wv = threadIdx.x >> 6, l = threadIdx.x & 63;
  int n = blockIdx.x*4 + wv;
  if (n >= NN) return;
  int start = off[n], deg = off[n+1] - start;
  int hl = l & 3, jl = l >> 2;
  float cl = P2[hl], cr = P2[4 + hl];
  float xd = X[n];
  float m = -INFINITY, ssum = 0.f, t = 0.f;
  for (int j = jl; j < deg; j += 16){
    int s = csr[start + j];
    float xs = X[s];
    float e = lrelu(xs*cl + xd*cr);
    if (e > m){
      float w = __expf(m - e);
      ssum = ssum*w + 1.f;
      t    = t*w + xs;
      m = e;
    } else {
      float w = __expf(e - m);
      ssum += w;
      t    = fmaf(w, xs, t);
    }
  }
  #pragma unroll
  for (int msk=4; msk<64; msk<<=1){
    float mo = __shfl_xor(m, msk), so = __shfl_xor(ssum, msk), to = __shfl_xor(t, msk);
    float mn = fmaxf(m, mo);
    if (mn > -INFINITY){
      float w1 = __expf(m - mn), w2 = __expf(mo - mn);
      ssum = ssum*w1 + so*w2;
      t    = t*w1 + to*w2;
    }
    m = mn;
  }
  float tv = t / (ssum + 1e-9f);
  float th = __shfl(tv, l >> 4);
  const float2 w2v = *(const float2*)(P + 2*l);
  const float2 b2v = *(const float2*)(P + 128 + 2*l);
  float2 o;
  o.x = fmaf(th, w2v.x, b2v.x);
  o.y = fmaf(th, w2v.y, b2v.y);
  *(float2*)(out + n*128 + 2*l) = o;
}

// ---------------- H=4 aggregation: ONE wave per node, all 4 heads.
// feat [n][128] bf16 (256B row = 2 full L2 lines, coalesced 16-lane gather);
// el/er [n][4] f32 (one 16B broadcast per edge). Wave: 4 edge-groups x 16
// lanes; lane q: head q>>2, dims (q&3)*8..+8 (uint4 = 8 bf16). Softmax per
// head via float4 component butterflies; alpha staged in LDS as float4.
// All shfl/LDS loops keep wave-uniform trip counts (R5 lesson).
template<bool ELU>
__global__ __launch_bounds__(256) void k_agg4(const int* __restrict__ off,
        const ushortT* __restrict__ csr, const ushortT* __restrict__ featb,
        const float* __restrict__ el4, const float* __restrict__ er4,
        const float* __restrict__ bias, float* __restrict__ out){
  __shared__ float4 aS[4][64];
  __shared__ int    sS[4][64];
  int wv = threadIdx.x >> 6, l = threadIdx.x & 63;
  int n = blockIdx.x*4 + wv;
  if (n >= NN) return;
  int start = off[n], deg = off[n+1] - start;
  const float4 ern = *(const float4*)(er4 + n*4);
  int g = l >> 4, q = l & 15, h = q >> 2, p = q & 3;
  float acc[8] = {0.f,0.f,0.f,0.f,0.f,0.f,0.f,0.f};
  float4 asum = make_float4(0.f,0.f,0.f,0.f);
  if (deg <= 64){
    int s = 0;
    float4 e4 = make_float4(-INFINITY,-INFINITY,-INFINITY,-INFINITY);
    if (l < deg){
      s = csr[start + l];
      const float4 elv = *(const float4*)(el4 + s*4);
      e4.x = lrelu(elv.x + ern.x); e4.y = lrelu(elv.y + ern.y);
      e4.z = lrelu(elv.z + ern.z); e4.w = lrelu(elv.w + ern.w);
    }
    float4 m4 = e4;
    #pragma unroll
    for (int msk=1; msk<64; msk<<=1){
      m4.x = fmaxf(m4.x, __shfl_xor(m4.x, msk));
      m4.y = fmaxf(m4.y, __shfl_xor(m4.y, msk));
      m4.z = fmaxf(m4.z, __shfl_xor(m4.z, msk));
      m4.w = fmaxf(m4.w, __shfl_xor(m4.w, msk));
    }
    float4 a4 = make_float4(0.f,0.f,0.f,0.f);
    if (l < deg){
      a4.x = __expf(e4.x - m4.x); a4.y = __expf(e4.y - m4.y);
      a4.z = __expf(e4.z - m4.z); a4.w = __expf(e4.w - m4.w);
    }
    asum = a4;
    aS[wv][l] = a4; sS[wv][l] = s;
    #pragma unroll 4
    for (int jj = 0; jj < deg; jj += 4){     // uniform trip count
      int e = jj + g;                        // <= 63; alpha==0 pads e >= deg
      float aj = ((const float*)&aS[wv][e])[h];
      int   sj = sS[wv][e];
      uint4 w = *(const uint4*)(featb + sj*128 + h*32 + p*8);
      acc[0] = fmaf(aj, bfl(w.x), acc[0]); acc[1] = fmaf(aj, bfh(w.x), acc[1]);
      acc[2] = fmaf(aj, bfl(w.y), acc[2]); acc[3] = fmaf(aj, bfh(w.y), acc[3]);
      acc[4] = fmaf(aj, bfl(w.z), acc[4]); acc[5] = fmaf(aj, bfh(w.z), acc[5]);
      acc[6] = fmaf(aj, bfl(w.w), acc[6]); acc[7] = fmaf(aj, bfh(w.w), acc[7]);
    }
  } else {
    float4 m4 = make_float4(-INFINITY,-INFINITY,-INFINITY,-INFINITY);
    for (int j0 = 0; j0 < deg; j0 += 64){
      int j = j0 + l;
      int s = 0;
      float4 e4 = make_float4(-INFINITY,-INFINITY,-INFINITY,-INFINITY);
      if (j < deg){
        s = csr[start + j];
        const float4 elv = *(const float4*)(el4 + s*4);
        e4.x = lrelu(elv.x + ern.x); e4.y = lrelu(elv.y + ern.y);
        e4.z = lrelu(elv.z + ern.z); e4.w = lrelu(elv.w + ern.w);
      }
      float4 cm = e4;
      #pragma unroll
      for (int msk=1; msk<64; msk<<=1){
        cm.x = fmaxf(cm.x, __shfl_xor(cm.x, msk));
        cm.y = fmaxf(cm.y, __shfl_xor(cm.y, msk));
        cm.z = fmaxf(cm.z, __shfl_xor(cm.z, msk));
        cm.w = fmaxf(cm.w, __shfl_xor(cm.w, msk));
      }
      float4 mn = make_float4(fmaxf(m4.x,cm.x), fmaxf(m4.y,cm.y),
                              fmaxf(m4.z,cm.z), fmaxf(m4.w,cm.w));
      float4 rs;
      rs.x = __expf(m4.x - mn.x); rs.y = __expf(m4.y - mn.y);   // 0 on 1st chunk
      rs.z = __expf(m4.z - mn.z); rs.w = __expf(m4.w - mn.w);
      float4 a4 = make_float4(0.f,0.f,0.f,0.f);
      if (j < deg){
        a4.x = __expf(e4.x - mn.x); a4.y = __expf(e4.y - mn.y);
        a4.z = __expf(e4.z - mn.z); a4.w = __expf(e4.w - mn.w);
      }
      asum.x = asum.x*rs.x + a4.x; asum.y = asum.y*rs.y + a4.y;
      asum.z = asum.z*rs.z + a4.z; asum.w = asum.w*rs.w + a4.w;
      float rh = ((const float*)&rs)[h];
      #pragma unroll
      for (int i=0;i<8;++i) acc[i] *= rh;
      m4 = mn;
      aS[wv][l] = a4; sS[wv][l] = s;
      int cnt = deg - j0; if (cnt > 64) cnt = 64;
      #pragma unroll 4
      for (int jj = 0; jj < cnt; jj += 4){
        int e = jj + g;
        float aj = ((const float*)&aS[wv][e])[h];
        int   sj = sS[wv][e];
        uint4 w = *(const uint4*)(featb + sj*128 + h*32 + p*8);
        acc[0] = fmaf(aj, bfl(w.x), acc[0]); acc[1] = fmaf(aj, bfh(w.x), acc[1]);
        acc[2] = fmaf(aj, bfl(w.y), acc[2]); acc[3] = fmaf(aj, bfh(w.y), acc[3]);
        acc[4] = fmaf(aj, bfl(w.z), acc[4]); acc[5] = fmaf(aj, bfh(w.z), acc[5]);
        acc[6] = fmaf(aj, bfl(w.w), acc[6]); acc[7] = fmaf(aj, bfh(w.w), acc[7]);
      }
    }
  }
  #pragma unroll
  for (int i=0;i<8;++i){
    acc[i] += __shfl_xor(acc[i], 16);
    acc[i] += __shfl_xor(acc[i], 32);
  }
  #pragma unroll
  for (int msk=1; msk<64; msk<<=1){
    asum.x += __shfl_xor(asum.x, msk);
    asum.y += __shfl_xor(asum.y, msk);
    asum.z += __shfl_xor(asum.z, msk);
    asum.w += __shfl_xor(asum.w, msk);
  }
  if (l < 16){
    float sinv = 1.f/(((const float*)&asum)[h] + 1e-9f);
    const float* bp = bias + h*32 + p*8;
    float o[8];
    #pragma unroll
    for (int i=0;i<8;++i){
      o[i] = fmaf(acc[i], sinv, bp[i]);
      if (ELU) o[i] = o[i] > 0.f ? o[i] : expm1f(o[i]);
    }
    float* op = out + n*128 + h*32 + p*8;
    *(float4*)op       = make_float4(o[0],o[1],o[2],o[3]);
    *(float4*)(op + 4) = make_float4(o[4],o[5],o[6],o[7]);
  }
}

// ---------------- H=1 aggregation (verified R13): feat [n][32] bf16, el/er [n]
template<bool ELU>
__global__ __launch_bounds__(256) void k_agg1(const int* __restrict__ off,
        const ushortT* __restrict__ csr, const ushortT* __restrict__ featb,
        const float* __restrict__ el, const float* __restrict__ er,
        const float* __restrict__ bias, float* __restrict__ out){
  __shared__ float2 as_[4][64];
  int wv = threadIdx.x >> 6, l = threadIdx.x & 63;
  int n = blockIdx.x*4 + wv;
  if (n >= NN) return;
  int start = off[n], deg = off[n+1] - start;
  float erl = er[n];
  int g = l >> 3, dl = l & 7;
  float4 acc = make_float4(0.f, 0.f, 0.f, 0.f);
  float asum = 0.f;
  if (deg <= 64){
    int s = 0; float e = -INFINITY;
    if (l < deg){ s = csr[start + l]; e = lrelu(el[s] + erl); }
    float m = e;
    #pragma unroll
    for (int msk=1; msk<64; msk<<=1) m = fmaxf(m, __shfl_xor(m, msk));
    float a = (l < deg) ? __expf(e - m) : 0.f;
    as_[wv][l] = make_float2(a, __int_as_float(s));
    #pragma unroll 4
    for (int jj = 0; jj < deg; jj += 8){
      float2 pr = as_[wv][jj + g];
      float aj = pr.x; int sj = __float_as_int(pr.y);
      uint2 w = *(const uint2*)(featb + sj*32 + 4*dl);
      acc.x = fmaf(aj, bfl(w.x), acc.x);
      acc.y = fmaf(aj, bfh(w.x), acc.y);
      acc.z = fmaf(aj, bfl(w.y), acc.z);
      acc.w = fmaf(aj, bfh(w.y), acc.w);
      asum += aj;
    }
  } else {
    float m = -INFINITY;
    for (int j0 = 0; j0 < deg; j0 += 64){
      int j = j0 + l;
      int s = 0; float e = -INFINITY;
      if (j < deg){ s = csr[start + j]; e = lrelu(el[s] + erl); }
      float cm = e;
      #pragma unroll
      for (int msk=1; msk<64; msk<<=1) cm = fmaxf(cm, __shfl_xor(cm, msk));
      float mn = fmaxf(m, cm);
      float rs = __expf(m - mn);
      float a = (j < deg) ? __expf(e - mn) : 0.f;
      acc.x *= rs; acc.y *= rs; acc.z *= rs; acc.w *= rs;
      asum *= rs;
      m = mn;
      as_[wv][l] = make_float2(a, __int_as_float(s));
      int cnt = deg - j0; if (cnt > 64) cnt = 64;
      #pragma unroll 4
      for (int jj = 0; jj < cnt; jj += 8){
        float2 pr = as_[wv][jj + g];
        float aj = pr.x; int sj = __float_as_int(pr.y);
        uint2 w = *(const uint2*)(featb + sj*32 + 4*dl);
        acc.x = fmaf(aj, bfl(w.x), acc.x);
        acc.y = fmaf(aj, bfh(w.x), acc.y);
        acc.z = fmaf(aj, bfl(w.y), acc.z);
        acc.w = fmaf(aj, bfh(w.y), acc.w);
        asum += aj;
      }
    }
  }
  #pragma unroll
  for (int msk=8; msk<64; msk<<=1){
    acc.x += __shfl_xor(acc.x, msk);
    acc.y += __shfl_xor(acc.y, msk);
    acc.z += __shfl_xor(acc.z, msk);
    acc.w += __shfl_xor(acc.w, msk);
    asum  += __shfl_xor(asum,  msk);
  }
  float sinv = 1.f/(asum + 1e-9f);
  if (l < 8){
    const float4 b4 = *(const float4*)(bias + 4*l);
    float o0 = fmaf(acc.x, sinv, b4.x);
    float o1 = fmaf(acc.y, sinv, b4.y);
    float o2 = fmaf(acc.z, sinv, b4.z);
    float o3 = fmaf(acc.w, sinv, b4.w);
    if (ELU){
      o0 = o0 > 0.f ? o0 : expm1f(o0);
      o1 = o1 > 0.f ? o1 : expm1f(o1);
      o2 = o2 > 0.f ? o2 : expm1f(o2);
      o3 = o3 > 0.f ? o3 : expm1f(o3);
    }
    *(float4*)(out + n*32 + 4*l) = make_float4(o0, o1, o2, o3);
  }
}

// ---------------- workspace layout (float elements) — ALL live buffers 512B-aligned
#define WS_P     0
#define WS_P2    22144
#define WS_EL    22272       // [n][H] f32, max NN*4 = 80000
#define WS_ER    102272
#define WS_FEAT  262144      // bf16 [n][OUT], max NN*128*2B = 1.28M floats
#define WS_ZA    2822144
#define WS_ZB    5382144
#define WS_OFFI  6022144
#define WS_OFFT  6042240
#define WS_CSRI  6423552
#define WS_CSRT  6743552
#define WS_TOTAL 7063552     // 28.25 MB (unchanged)
// CSR-build scratch ALIASED into feat+zA region (dead until k_l1 / layer 2):
#define WS_HB    (WS_FEAT + 0)        // histB: 160 * 10000 ints
#define WS_BS    (WS_FEAT + 1600000)  // bases: 160 * 20000 ints
#define WS_EXC   (WS_FEAT + 4800000)  // 40*1024 ints
#define WS_BSUM  (WS_FEAT + 4841472)  // 40 ints
#define WS_BBASE (WS_FEAT + 4841600)  // 40 ints

extern "C" void kernel_launch(void* const* d_in, const int* in_sizes, int n_in,
                              void* d_out, int out_size, void* d_ws, size_t ws_size,
                              hipStream_t stream) {
  if (ws_size < (size_t)WS_TOTAL * sizeof(float)) {
    hipMemsetAsync(d_out, 0, (size_t)out_size * sizeof(float), stream);
    return;
  }
  const float* X      = (const float*)d_in[0];
  const float* m1     = (const float*)d_in[1];
  const float* mt     = (const float*)d_in[2];
  const float* Whin   = (const float*)d_in[3];
  const float* bhin   = (const float*)d_in[4];
  const float* Whout  = (const float*)d_in[5];
  const float* bhout  = (const float*)d_in[6];
  const int* src_in   = (const int*)d_in[7];
  const int* dst_in   = (const int*)d_in[8];
  const int* src_trg  = (const int*)d_in[9];
  const int* dst_trg  = (const int*)d_in[10];
  float* out = (float*)d_out;
  float* ws  = (float*)d_ws;

  float* P    = ws + WS_P;
  float* P2   = ws + WS_P2;
  float* el   = ws + WS_EL;
  float* er   = ws + WS_ER;
  ushortT* featb = (ushortT*)(ws + WS_FEAT);
  float* zA   = ws + WS_ZA;
  float* zB   = ws + WS_ZB;
  int* off_in  = (int*)(ws + WS_OFFI);
  int* off_trg = (int*)(ws + WS_OFFT);
  int* histB   = (int*)(ws + WS_HB);
  int* bases   = (int*)(ws + WS_BS);
  int* exc     = (int*)(ws + WS_EXC);
  int* bsum    = (int*)(ws + WS_BSUM);
  int* bbase   = (int*)(ws + WS_BBASE);
  ushortT* csr_in  = (ushortT*)(ws + WS_CSRI);
  ushortT* csr_trg = (ushortT*)(ws + WS_CSRT);

  // params + histograms (fused, independent block ranges)
  k_prmhist<<<2*NCH + 87, 256, 0, stream>>>(m1, mt, Whin, bhin, Whout, bhout, P,
                                            dst_in, dst_trg, histB);
  k_csrA<<<40, 1024, 0, stream>>>(histB, exc, bsum);
  k_csrB<<<1, 64, 0, stream>>>(bsum, bbase, off_in, off_trg, P, P2);
  k_csrC<<<40, 1024, 0, stream>>>(histB, exc, bbase, off_in, off_trg, bases);
  k_fillL<<<4*NCH, 256, 0, stream>>>(src_in, dst_in, src_trg, dst_trg, bases,
                                     csr_in, csr_trg);

  // Layer 1: fused (H=4, in=1) -> zA (N x 128)
  k_l1<<<NB4C, 256, 0, stream>>>(off_in, csr_in, X, P, P2, zA);

  // Layer 2: H=1, in=128 -> zB (N x 32), ELU
  k_featel<128,32,1><<<(NN*32)/256, 256, 0, stream>>>(zA, P+512, P+4640, P+4672, featb, el, er);
  k_agg1<true><<<NB4C, 256, 0, stream>>>(off_in, csr_in, featb, el, er, P+4608, zB);

  // Layer 3: H=4, in=32 -> zA (N x 128)
  k_featel<32,128,4><<<(NN*128)/256, 256, 0, stream>>>(zB, P+4704, P+8928, P+9056, featb, el, er);
  k_agg4<false><<<NB4C, 256, 0, stream>>>(off_trg, csr_trg, featb, el, er, P+8800, zA);

  // Layer 4: H=1, in=128 -> zB (N x 32), ELU
  k_featel<128,32,1><<<(NN*32)/256, 256, 0, stream>>>(zA, P+9184, P+13312, P+13344, featb, el, er);
  k_agg1<true><<<NB4C, 256, 0, stream>>>(off_trg, csr_trg, featb, el, er, P+13280, zB);

  // Layer 5: H=4, in=32 -> zA (N x 128)
  k_featel<32,128,4><<<(NN*128)/256, 256, 0, stream>>>(zB, P+13376, P+17600, P+17728, featb, el, er);
  k_agg4<false><<<NB4C, 256, 0, stream>>>(off_trg, csr_trg, featb, el, er, P+17472, zA);

  // Layer 6: H=1, in=128 -> out (N x 32), ELU
  k_featel<128,32,1><<<(NN*32)/256, 256, 0, stream>>>(zA, P+17856, P+21984, P+22016, featb, el, er);
  k_agg1<true><<<NB4C, 256, 0, stream>>>(off_trg, csr_trg, featb, el, er, P+21952, out);
}

// Round 15
// 308.593 us; speedup vs baseline: 1.0036x; 1.0036x over previous
//
#include <hip/hip_runtime.h>
#include <math.h>

#define NN 20000
#define EE 640000
#define NB4C 5000
#define NCH 80          // edge chunks per graph
#define CHE 8000        // edges per chunk (NCH*CHE == EE)

typedef unsigned short ushortT;
typedef unsigned int uintT;

__device__ __forceinline__ float lrelu(float x){ return x >= 0.f ? x : 0.2f*x; }
__device__ __forceinline__ ushortT f2bf(float x){
  uintT u = __float_as_uint(x);
  u = (u + 0x7FFFu + ((u >> 16) & 1u)) >> 16;   // RNE
  return (ushortT)u;
}
__device__ __forceinline__ float bfl(uintT w){ return __uint_as_float(w << 16); }
__device__ __forceinline__ float bfh(uintT w){ return __uint_as_float(w & 0xFFFF0000u); }

// ---------------- fused: metadata GEMV+pack (P, 22048 floats)  UNION  LDS histogram
// P layout: W1@0(128) B1@128 AL1@256 AR1@384 / W2@512 B2@4608 AL2@4640 AR2@4672
// W3@4704 B3@8800 AL3@8928 AR3@9056 / W4@9184 B4@13280 AL4@13312 AR4@13344
// W5@13376 B5@17472 AL5@17600 AR5@17728 / W6@17856 B6@21952 AL6@21984 AR6@22016
__global__ __launch_bounds__(256) void k_prmhist(const float* __restrict__ m1,
        const float* __restrict__ mt, const float* __restrict__ Whin,
        const float* __restrict__ bhin, const float* __restrict__ Whout,
        const float* __restrict__ bhout, float* __restrict__ P,
        const int* __restrict__ dst_in, const int* __restrict__ dst_trg,
        int* __restrict__ histB){
  __shared__ int hist[NN/2];
  int b = blockIdx.x;
  if (b < 2*NCH){
    int g = b / NCH, c = b % NCH;
    const int* dst = g ? dst_trg : dst_in;
    for (int i=threadIdx.x; i<NN/2; i+=256) hist[i] = 0;
    __syncthreads();
    int e0 = c*CHE;
    for (int k=threadIdx.x; k<CHE; k+=256){
      int d = dst[e0+k];
      atomicAdd(&hist[d>>1], (d&1) ? 65536 : 1);
    }
    __syncthreads();
    int* outp = histB + b*(NN/2);
    for (int i=threadIdx.x; i<NN/2; i+=256) outp[i] = hist[i];
    return;
  }
  int t = (b - 2*NCH)*256 + threadIdx.x;
  if (t >= 22048) return;
  int sj; bool inA;
  if      (t < 128)  { sj = 256+t;          inA=true; }
  else if (t < 256)  { sj = 384+(t-128);    inA=true; }
  else if (t < 384)  { sj = t-256;          inA=true; }
  else if (t < 512)  { sj = 128+(t-384);    inA=true; }
  else if (t < 4608) { sj = 576+(t-512);    inA=true; }
  else if (t < 4640) { sj = 4672+(t-4608);  inA=true; }
  else if (t < 4672) { sj = 512+(t-4640);   inA=true; }
  else if (t < 4704) { sj = 544+(t-4672);   inA=true; }
  else { inA=false;
    if      (t < 8800)  { int k=t-4704, o=k>>5, i=k&31; sj = 768 + (o>>5)*3072+(o&31)*32+i; }
    else if (t < 8928)  { int o=t-8800; sj = 13056 + (o>>5)*96+(o&31); }
    else if (t < 9056)  { int q=t-8928;       sj = (q>>6)*192+(q&63); }
    else if (t < 9184)  { int q=(t-9056)+128; sj = (q>>6)*192+(q&63); }
    else if (t < 13280) { sj = 13632 + (t-9184); }
    else if (t < 13312) { sj = 25920 + (t-13280); }
    else if (t < 13344) { sj = 13440 + (t-13312); }
    else if (t < 13376) { sj = 13472 + (t-13344); }
    else if (t < 17472) { int k=t-13376, o=k>>5, i=k&31; sj = 768 + (o>>5)*3072+(32+(o&31))*32+i; }
    else if (t < 17600) { int o=t-17472; sj = 13056 + (o>>5)*96+32+(o&31); }
    else if (t < 17728) { int q=t-17600;       sj = (q>>6)*192+64+(q&63); }
    else if (t < 17856) { int q=(t-17728)+128; sj = (q>>6)*192+64+(q&63); }
    else if (t < 21952) { sj = 13632+4096+(t-17856); }
    else if (t < 21984) { sj = 25920+32+(t-21952); }
    else if (t < 22016) { sj = 13440+64+(t-21984); }
    else                { sj = 13440+96+(t-22016); }
  }
  float acc;
  if (inA){
    acc = bhin[sj];
    #pragma unroll 8
    for (int k=0;k<64;++k) acc = fmaf(m1[k], Whin[k*4704 + sj], acc);
  } else {
    acc = bhout[sj];
    #pragma unroll 8
    for (int k=0;k<64;++k) acc = fmaf(mt[k], Whout[k*26016 + sj], acc);
  }
  P[t] = acc;
}

// ---- 2-level scan of per-node totals (fold of 80 chunk planes) -> off
__global__ __launch_bounds__(1024) void k_csrA(const int* __restrict__ histB,
        int* __restrict__ exc, int* __restrict__ bsum){
  int b = blockIdx.x, t = threadIdx.x;      // 40 blocks
  int g = b/20, c2 = b%20;
  int i = c2*1024 + t;
  int tot = 0;
  if (i < NN){
    int sh = (i&1)*16;
    for (int cb=0; cb<NCH; ++cb){
      int w = histB[(g*NCH+cb)*(NN/2) + (i>>1)];
      tot += (w >> sh) & 0xFFFF;
    }
  }
  __shared__ int s[1024];
  s[t] = tot;
  __syncthreads();
  for (int d=1; d<1024; d<<=1){
    int v = (t>=d) ? s[t-d] : 0;
    __syncthreads();
    s[t] += v;
    __syncthreads();
  }
  exc[b*1024 + t] = s[t] - tot;
  if (t == 1023) bsum[b] = s[t];
}

// serial fold of 40 block sums + P2 dots + off[NN]
__global__ void k_csrB(const int* __restrict__ bsum, int* __restrict__ bbase,
        int* __restrict__ off_in, int* __restrict__ off_trg,
        const float* __restrict__ P, float* __restrict__ P2){
  int t = threadIdx.x;
  if (t < 8){
    int hh = t >> 1, sel = t & 1;
    const float* W = P;
    const float* A = P + 256 + sel*128;
    float c = 0.f;
    #pragma unroll 8
    for (int d=0; d<32; ++d) c = fmaf(W[hh*32+d], A[hh*32+d], c);
    P2[sel*4 + hh] = c;
  } else if (t == 8){
    int base = 0;
    for (int b=0; b<20; ++b){ bbase[b] = base; base += bsum[b]; }
  } else if (t == 9){
    int base = 0;
    for (int b=20; b<40; ++b){ bbase[b] = base; base += bsum[b]; }
  } else if (t == 10) off_in[NN]  = EE;
  else if   (t == 11) off_trg[NN] = EE;
}

// merged: off[i] write + per-chunk running prefix -> bases[g][chunk][node]
__global__ __launch_bounds__(1024) void k_csrC(const int* __restrict__ histB,
        const int* __restrict__ exc, const int* __restrict__ bbase,
        int* __restrict__ off_in, int* __restrict__ off_trg,
        int* __restrict__ bases){
  int b = blockIdx.x, t = threadIdx.x;      // 40 blocks
  int g = b/20, c2 = b%20;
  int i = c2*1024 + t;
  if (i >= NN) return;
  int* off = g ? off_trg : off_in;
  int running = exc[b*1024 + t] + bbase[b];
  off[i] = running;
  int sh = (i&1)*16;
  for (int cb=0; cb<NCH; ++cb){
    bases[(g*NCH+cb)*NN + i] = running;
    int w = histB[(g*NCH+cb)*(NN/2) + (i>>1)];
    running += (w >> sh) & 0xFFFF;
  }
}

// fill: block = (graph, node-half, chunk); LDS bump allocator (no global atomic returns)
__global__ __launch_bounds__(256) void k_fillL(const int* __restrict__ src_in,
        const int* __restrict__ dst_in, const int* __restrict__ src_trg,
        const int* __restrict__ dst_trg, const int* __restrict__ bases,
        ushortT* __restrict__ csr_in, ushortT* __restrict__ csr_trg){
  int b = blockIdx.x;                  // 0..319
  int g = b / (2*NCH);
  int rem = b % (2*NCH);
  int half = rem / NCH, c = rem % NCH;
  const int* src = g ? src_trg : src_in;
  const int* dst = g ? dst_trg : dst_in;
  ushortT* csr = g ? csr_trg : csr_in;
  __shared__ int alloc[NN/2];
  const int* basep = bases + (g*NCH+c)*NN + half*(NN/2);
  for (int i=threadIdx.x; i<NN/2; i+=256) alloc[i] = basep[i];
  __syncthreads();
  int e0 = c*CHE;
  int lo = half*(NN/2);
  for (int k=threadIdx.x; k<CHE; k+=256){
    int d = dst[e0+k];
    int dl = d - lo;
    if ((unsigned)dl < (unsigned)(NN/2)){
      int p = atomicAdd(&alloc[dl], 1);
      csr[p] = (ushortT)src[e0+k];
    }
  }
}

// ---------------- fused feat+el/er; feat stored BF16 TRANSPOSED [h][NN][32]
template<int IN, int OUT, int H>
__global__ __launch_bounds__(256) void k_featel(const float* __restrict__ z,
        const float* __restrict__ W, const float* __restrict__ AL,
        const float* __restrict__ AR, ushortT* __restrict__ featb,
        float* __restrict__ el, float* __restrict__ er){
  __shared__ float Ws[IN*(OUT+1)];
  __shared__ float ALs[OUT], ARs[OUT];
  for (int idx=threadIdx.x; idx<IN*OUT; idx+=256){
    int o = idx / IN, i = idx % IN;
    Ws[i*(OUT+1) + o] = W[idx];
  }
  for (int idx=threadIdx.x; idx<OUT; idx+=256){ ALs[idx]=AL[idx]; ARs[idx]=AR[idx]; }
  __syncthreads();
  int tid = blockIdx.x*256 + threadIdx.x;
  int n = tid / OUT, o = tid % OUT;
  const float4* z4 = (const float4*)(z + n*IN);
  float acc = 0.f;
  #pragma unroll
  for (int i=0;i<IN/4;++i){
    float4 zv = z4[i];
    acc = fmaf(zv.x, Ws[(4*i+0)*(OUT+1)+o], acc);
    acc = fmaf(zv.y, Ws[(4*i+1)*(OUT+1)+o], acc);
    acc = fmaf(zv.z, Ws[(4*i+2)*(OUT+1)+o], acc);
    acc = fmaf(zv.w, Ws[(4*i+3)*(OUT+1)+o], acc);
  }
  int h = o >> 5, d = o & 31;
  featb[(h*NN + n)*32 + d] = f2bf(acc);
  float a = acc * ALs[o], b = acc * ARs[o];
  #pragma unroll
  for (int msk=1; msk<32; msk<<=1){
    a += __shfl_xor(a, msk);
    b += __shfl_xor(b, msk);
  }
  if (d == 0){
    el[h*NN + n] = a;
    er[h*NN + n] = b;
  }
}

// ---------------- layer 1 fused (IN=1 algebraic collapse) — f32 path, unchanged
__global__ __launch_bounds__(256) void k_l1(const int* __restrict__ off,
        const ushortT* __restrict__ csr, const float* __restrict__ X,
        const float* __restrict__ P, const float* __restrict__ P2,
        float* __restrict__ out){
  int wv = threadIdx.x >> 6, l = threadIdx.x & 63;
  int n = blockIdx.x*4 + wv;
  if (n >= NN) return;
  int start = off[n], deg = off[n+1] - start;
  int hl = l & 3, jl = l >> 2;
  float cl = P2[hl], cr = P2[4 + hl];
  float xd = X[n];
  float m = -INFINITY, ssum = 0.f, t = 0.f;
  for (int j = jl; j < deg; j += 16){
    int s = csr[start + j];
    float xs = X[s];
    float e = lrelu(xs*cl + xd*cr);
    if (e > m){
      float w = __expf(m - e);
      ssum = ssum*w + 1.f;
      t    = t*w + xs;
      m = e;
    } else {
      float w = __expf(e - m);
      ssum += w;
      t    = fmaf(w, xs, t);
    }
  }
  #pragma unroll
  for (int msk=4; msk<64; msk<<=1){
    float mo = __shfl_xor(m, msk), so = __shfl_xor(ssum, msk), to = __shfl_xor(t, msk);
    float mn = fmaxf(m, mo);
    if (mn > -INFINITY){
      float w1 = __expf(m - mn), w2 = __expf(mo - mn);
      ssum = ssum*w1 + so*w2;
      t    = t*w1 + to*w2;
    }
    m = mn;
  }
  float tv = t / (ssum + 1e-9f);
  float th = __shfl(tv, l >> 4);
  const float2 w2v = *(const float2*)(P + 2*l);
  const float2 b2v = *(const float2*)(P + 128 + 2*l);
  float2 o;
  o.x = fmaf(th, w2v.x, b2v.x);
  o.y = fmaf(th, w2v.y, b2v.y);
  *(float2*)(out + n*128 + 2*l) = o;
}

// ---------------- aggregation: wave per (node, head), phase-major grid (verified R13).
// R15 change: PV inner loop widened to 16 edge-groups x 4 lanes x uint4 (16B/lane,
// 4 lanes cover the 64B bf16 row) — half the trips of the 8x8xuint2 form, 8
// independent FMA chains for ILP. (R14 lesson: keep head-split TLP — merged-head
// wave cut occupancy 70%->28% and regressed.)
// All shfl/LDS loops keep wave-uniform trip counts (R5 lesson).
template<int H, bool ELU>
__global__ __launch_bounds__(256) void k_aggH(const int* __restrict__ off,
        const ushortT* __restrict__ csr, const ushortT* __restrict__ featb,
        const float* __restrict__ el, const float* __restrict__ er,
        const float* __restrict__ bias, float* __restrict__ out){
  __shared__ float2 as_[4][64];
  int wv = threadIdx.x >> 6, l = threadIdx.x & 63;
  int bid = blockIdx.x;
  int h = bid / NB4C, b = bid % NB4C;
  int n = b*4 + wv;
  if (n >= NN) return;
  const float* elh = el + h*NN;
  const ushortT* fh = featb + (size_t)h*NN*32;
  int start = off[n], deg = off[n+1] - start;
  float erl = er[h*NN + n];
  int g = l >> 2, dl = l & 3;   // 16 edge-groups x 4 lanes; uint4 (8 bf16) per lane
  float acc[8] = {0.f,0.f,0.f,0.f,0.f,0.f,0.f,0.f};
  float asum = 0.f;
  if (deg <= 64){
    int s = 0; float e = -INFINITY;
    if (l < deg){ s = csr[start + l]; e = lrelu(elh[s] + erl); }
    float m = e;
    #pragma unroll
    for (int msk=1; msk<64; msk<<=1) m = fmaxf(m, __shfl_xor(m, msk));
    float a = (l < deg) ? __expf(e - m) : 0.f;
    as_[wv][l] = make_float2(a, __int_as_float(s));
    #pragma unroll 4
    for (int jj = 0; jj < deg; jj += 16){      // uniform trip count
      float2 p = as_[wv][jj + g];              // jj+g <= 48+15 = 63
      float aj = p.x; int sj = __float_as_int(p.y);
      uint4 w = *(const uint4*)(fh + sj*32 + 8*dl);
      acc[0] = fmaf(aj, bfl(w.x), acc[0]); acc[1] = fmaf(aj, bfh(w.x), acc[1]);
      acc[2] = fmaf(aj, bfl(w.y), acc[2]); acc[3] = fmaf(aj, bfh(w.y), acc[3]);
      acc[4] = fmaf(aj, bfl(w.z), acc[4]); acc[5] = fmaf(aj, bfh(w.z), acc[5]);
      acc[6] = fmaf(aj, bfl(w.w), acc[6]); acc[7] = fmaf(aj, bfh(w.w), acc[7]);
      asum += aj;
    }
  } else {
    float m = -INFINITY;
    for (int j0 = 0; j0 < deg; j0 += 64){
      int j = j0 + l;
      int s = 0; float e = -INFINITY;
      if (j < deg){ s = csr[start + j]; e = lrelu(elh[s] + erl); }
      float cm = e;
      #pragma unroll
      for (int msk=1; msk<64; msk<<=1) cm = fmaxf(cm, __shfl_xor(cm, msk));
      float mn = fmaxf(m, cm);
      float rs = __expf(m - mn);     // 0 on first chunk (m=-inf), acc/asum are 0
      float a = (j < deg) ? __expf(e - mn) : 0.f;
      #pragma unroll
      for (int i=0;i<8;++i) acc[i] *= rs;
      asum *= rs;
      m = mn;
      as_[wv][l] = make_float2(a, __int_as_float(s));
      int cnt = deg - j0; if (cnt > 64) cnt = 64;
      #pragma unroll 4
      for (int jj = 0; jj < cnt; jj += 16){
        float2 p = as_[wv][jj + g];
        float aj = p.x; int sj = __float_as_int(p.y);
        uint4 w = *(const uint4*)(fh + sj*32 + 8*dl);
        acc[0] = fmaf(aj, bfl(w.x), acc[0]); acc[1] = fmaf(aj, bfh(w.x), acc[1]);
        acc[2] = fmaf(aj, bfl(w.y), acc[2]); acc[3] = fmaf(aj, bfh(w.y), acc[3]);
        acc[4] = fmaf(aj, bfl(w.z), acc[4]); acc[5] = fmaf(aj, bfh(w.z), acc[5]);
        acc[6] = fmaf(aj, bfl(w.w), acc[6]); acc[7] = fmaf(aj, bfh(w.w), acc[7]);
        asum += aj;
      }
    }
  }
  #pragma unroll
  for (int msk=4; msk<64; msk<<=1){
    #pragma unroll
    for (int i=0;i<8;++i) acc[i] += __shfl_xor(acc[i], msk);
    asum += __shfl_xor(asum, msk);
  }
  if (l < 4){
    float sinv = 1.f/(asum + 1e-9f);
    const float* bp = bias + h*32 + l*8;
    float o[8];
    #pragma unroll
    for (int i=0;i<8;++i){
      o[i] = fmaf(acc[i], sinv, bp[i]);
      if (ELU) o[i] = o[i] > 0.f ? o[i] : expm1f(o[i]);
    }
    float* op = out + n*(H*32) + h*32 + l*8;
    *(float4*)op       = make_float4(o[0],o[1],o[2],o[3]);
    *(float4*)(op + 4) = make_float4(o[4],o[5],o[6],o[7]);
  }
}

// ---------------- workspace layout (float elements) — ALL live buffers 512B-aligned
#define WS_P     0
#define WS_P2    22144
#define WS_EL    22272
#define WS_ER    102272
#define WS_FEAT  262144      // bf16 [h][NN][32], max 4*NN*32*2B
#define WS_ZA    2822144
#define WS_ZB    5382144
#define WS_OFFI  6022144
#define WS_OFFT  6042240
#define WS_CSRI  6423552
#define WS_CSRT  6743552
#define WS_TOTAL 7063552     // 28.25 MB (unchanged)
// CSR-build scratch ALIASED into feat+zA region (dead until k_l1 / layer 2):
#define WS_HB    (WS_FEAT + 0)        // histB: 160 * 10000 ints
#define WS_BS    (WS_FEAT + 1600000)  // bases: 160 * 20000 ints
#define WS_EXC   (WS_FEAT + 4800000)  // 40*1024 ints
#define WS_BSUM  (WS_FEAT + 4841472)  // 40 ints
#define WS_BBASE (WS_FEAT + 4841600)  // 40 ints

extern "C" void kernel_launch(void* const* d_in, const int* in_sizes, int n_in,
                              void* d_out, int out_size, void* d_ws, size_t ws_size,
                              hipStream_t stream) {
  if (ws_size < (size_t)WS_TOTAL * sizeof(float)) {
    hipMemsetAsync(d_out, 0, (size_t)out_size * sizeof(float), stream);
    return;
  }
  const float* X      = (const float*)d_in[0];
  const float* m1     = (const float*)d_in[1];
  const float* mt     = (const float*)d_in[2];
  const float* Whin   = (const float*)d_in[3];
  const float* bhin   = (const float*)d_in[4];
  const float* Whout  = (const float*)d_in[5];
  const float* bhout  = (const float*)d_in[6];
  const int* src_in   = (const int*)d_in[7];
  const int* dst_in   = (const int*)d_in[8];
  const int* src_trg  = (const int*)d_in[9];
  const int* dst_trg  = (const int*)d_in[10];
  float* out = (float*)d_out;
  float* ws  = (float*)d_ws;

  float* P    = ws + WS_P;
  float* P2   = ws + WS_P2;
  float* el   = ws + WS_EL;
  float* er   = ws + WS_ER;
  ushortT* featb = (ushortT*)(ws + WS_FEAT);
  float* zA   = ws + WS_ZA;
  float* zB   = ws + WS_ZB;
  int* off_in  = (int*)(ws + WS_OFFI);
  int* off_trg = (int*)(ws + WS_OFFT);
  int* histB   = (int*)(ws + WS_HB);
  int* bases   = (int*)(ws + WS_BS);
  int* exc     = (int*)(ws + WS_EXC);
  int* bsum    = (int*)(ws + WS_BSUM);
  int* bbase   = (int*)(ws + WS_BBASE);
  ushortT* csr_in  = (ushortT*)(ws + WS_CSRI);
  ushortT* csr_trg = (ushortT*)(ws + WS_CSRT);

  // params + histograms (fused, independent block ranges)
  k_prmhist<<<2*NCH + 87, 256, 0, stream>>>(m1, mt, Whin, bhin, Whout, bhout, P,
                                            dst_in, dst_trg, histB);
  k_csrA<<<40, 1024, 0, stream>>>(histB, exc, bsum);
  k_csrB<<<1, 64, 0, stream>>>(bsum, bbase, off_in, off_trg, P, P2);
  k_csrC<<<40, 1024, 0, stream>>>(histB, exc, bbase, off_in, off_trg, bases);
  k_fillL<<<4*NCH, 256, 0, stream>>>(src_in, dst_in, src_trg, dst_trg, bases,
                                     csr_in, csr_trg);

  // Layer 1: fused (H=4, in=1) -> zA (N x 128)
  k_l1<<<NB4C, 256, 0, stream>>>(off_in, csr_in, X, P, P2, zA);

  // Layer 2: H=1, in=128 -> zB (N x 32), ELU
  k_featel<128,32,1><<<(NN*32)/256, 256, 0, stream>>>(zA, P+512, P+4640, P+4672, featb, el, er);
  k_aggH<1,true><<<NB4C, 256, 0, stream>>>(off_in, csr_in, featb, el, er, P+4608, zB);

  // Layer 3: H=4, in=32 -> zA (N x 128)
  k_featel<32,128,4><<<(NN*128)/256, 256, 0, stream>>>(zB, P+4704, P+8928, P+9056, featb, el, er);
  k_aggH<4,false><<<4*NB4C, 256, 0, stream>>>(off_trg, csr_trg, featb, el, er, P+8800, zA);

  // Layer 4: H=1, in=128 -> zB (N x 32), ELU
  k_featel<128,32,1><<<(NN*32)/256, 256, 0, stream>>>(zA, P+9184, P+13312, P+13344, featb, el, er);
  k_aggH<1,true><<<NB4C, 256, 0, stream>>>(off_trg, csr_trg, featb, el, er, P+13280, zB);

  // Layer 5: H=4, in=32 -> zA (N x 128)
  k_featel<32,128,4><<<(NN*128)/256, 256, 0, stream>>>(zB, P+13376, P+17600, P+17728, featb, el, er);
  k_aggH<4,false><<<4*NB4C, 256, 0, stream>>>(off_trg, csr_trg, featb, el, er, P+17472, zA);

  // Layer 6: H=1, in=128 -> out (N x 32), ELU
  k_featel<128,32,1><<<(NN*32)/256, 256, 0, stream>>>(zA, P+17856, P+21984, P+22016, featb, el, er);
  k_aggH<1,true><<<NB4C, 256, 0, stream>>>(off_trg, csr_trg, featb, el, er, P+21952, out);
}

// Round 16
// 253.435 us; speedup vs baseline: 1.2220x; 1.2176x over previous
//
#include <hip/hip_runtime.h>
#include <math.h>

#define NN 20000
#define EE 640000
#define NB4C 5000
#define NCH 80          // edge chunks per graph
#define CHE 8000        // edges per chunk (NCH*CHE == EE)

typedef unsigned short ushortT;
typedef unsigned int uintT;

__device__ __forceinline__ float lrelu(float x){ return x >= 0.f ? x : 0.2f*x; }
__device__ __forceinline__ ushortT f2bf(float x){
  uintT u = __float_as_uint(x);
  u = (u + 0x7FFFu + ((u >> 16) & 1u)) >> 16;   // RNE
  return (ushortT)u;
}
__device__ __forceinline__ float bfl(uintT w){ return __uint_as_float(w << 16); }
__device__ __forceinline__ float bfh(uintT w){ return __uint_as_float(w & 0xFFFF0000u); }

// ---------------- fused: metadata GEMV+pack (P, 22048 floats)  UNION  LDS histogram
// P layout: W1@0(128) B1@128 AL1@256 AR1@384 / W2@512 B2@4608 AL2@4640 AR2@4672
// W3@4704 B3@8800 AL3@8928 AR3@9056 / W4@9184 B4@13280 AL4@13312 AR4@13344
// W5@13376 B5@17472 AL5@17600 AR5@17728 / W6@17856 B6@21952 AL6@21984 AR6@22016
__global__ __launch_bounds__(256) void k_prmhist(const float* __restrict__ m1,
        const float* __restrict__ mt, const float* __restrict__ Whin,
        const float* __restrict__ bhin, const float* __restrict__ Whout,
        const float* __restrict__ bhout, float* __restrict__ P,
        const int* __restrict__ dst_in, const int* __restrict__ dst_trg,
        int* __restrict__ histB){
  __shared__ int hist[NN/2];
  int b = blockIdx.x;
  if (b < 2*NCH){
    int g = b / NCH, c = b % NCH;
    const int* dst = g ? dst_trg : dst_in;
    for (int i=threadIdx.x; i<NN/2; i+=256) hist[i] = 0;
    __syncthreads();
    int e0 = c*CHE;
    for (int k=threadIdx.x; k<CHE; k+=256){
      int d = dst[e0+k];
      atomicAdd(&hist[d>>1], (d&1) ? 65536 : 1);
    }
    __syncthreads();
    int* outp = histB + b*(NN/2);
    for (int i=threadIdx.x; i<NN/2; i+=256) outp[i] = hist[i];
    return;
  }
  int t = (b - 2*NCH)*256 + threadIdx.x;
  if (t >= 22048) return;
  int sj; bool inA;
  if      (t < 128)  { sj = 256+t;          inA=true; }
  else if (t < 256)  { sj = 384+(t-128);    inA=true; }
  else if (t < 384)  { sj = t-256;          inA=true; }
  else if (t < 512)  { sj = 128+(t-384);    inA=true; }
  else if (t < 4608) { sj = 576+(t-512);    inA=true; }
  else if (t < 4640) { sj = 4672+(t-4608);  inA=true; }
  else if (t < 4672) { sj = 512+(t-4640);   inA=true; }
  else if (t < 4704) { sj = 544+(t-4672);   inA=true; }
  else { inA=false;
    if      (t < 8800)  { int k=t-4704, o=k>>5, i=k&31; sj = 768 + (o>>5)*3072+(o&31)*32+i; }
    else if (t < 8928)  { int o=t-8800; sj = 13056 + (o>>5)*96+(o&31); }
    else if (t < 9056)  { int q=t-8928;       sj = (q>>6)*192+(q&63); }
    else if (t < 9184)  { int q=(t-9056)+128; sj = (q>>6)*192+(q&63); }
    else if (t < 13280) { sj = 13632 + (t-9184); }
    else if (t < 13312) { sj = 25920 + (t-13280); }
    else if (t < 13344) { sj = 13440 + (t-13312); }
    else if (t < 13376) { sj = 13472 + (t-13344); }
    else if (t < 17472) { int k=t-13376, o=k>>5, i=k&31; sj = 768 + (o>>5)*3072+(32+(o&31))*32+i; }
    else if (t < 17600) { int o=t-17472; sj = 13056 + (o>>5)*96+32+(o&31); }
    else if (t < 17728) { int q=t-17600;       sj = (q>>6)*192+64+(q&63); }
    else if (t < 17856) { int q=(t-17728)+128; sj = (q>>6)*192+64+(q&63); }
    else if (t < 21952) { sj = 13632+4096+(t-17856); }
    else if (t < 21984) { sj = 25920+32+(t-21952); }
    else if (t < 22016) { sj = 13440+64+(t-21984); }
    else                { sj = 13440+96+(t-22016); }
  }
  float acc;
  if (inA){
    acc = bhin[sj];
    #pragma unroll 8
    for (int k=0;k<64;++k) acc = fmaf(m1[k], Whin[k*4704 + sj], acc);
  } else {
    acc = bhout[sj];
    #pragma unroll 8
    for (int k=0;k<64;++k) acc = fmaf(mt[k], Whout[k*26016 + sj], acc);
  }
  P[t] = acc;
}

// ---- 2-level scan of per-node totals (fold of 80 chunk planes) -> off
__global__ __launch_bounds__(1024) void k_csrA(const int* __restrict__ histB,
        int* __restrict__ exc, int* __restrict__ bsum){
  int b = blockIdx.x, t = threadIdx.x;      // 40 blocks
  int g = b/20, c2 = b%20;
  int i = c2*1024 + t;
  int tot = 0;
  if (i < NN){
    int sh = (i&1)*16;
    for (int cb=0; cb<NCH; ++cb){
      int w = histB[(g*NCH+cb)*(NN/2) + (i>>1)];
      tot += (w >> sh) & 0xFFFF;
    }
  }
  __shared__ int s[1024];
  s[t] = tot;
  __syncthreads();
  for (int d=1; d<1024; d<<=1){
    int v = (t>=d) ? s[t-d] : 0;
    __syncthreads();
    s[t] += v;
    __syncthreads();
  }
  exc[b*1024 + t] = s[t] - tot;
  if (t == 1023) bsum[b] = s[t];
}

// serial fold of 40 block sums + P2 dots + off[NN]
__global__ void k_csrB(const int* __restrict__ bsum, int* __restrict__ bbase,
        int* __restrict__ off_in, int* __restrict__ off_trg,
        const float* __restrict__ P, float* __restrict__ P2){
  int t = threadIdx.x;
  if (t < 8){
    int hh = t >> 1, sel = t & 1;
    const float* W = P;
    const float* A = P + 256 + sel*128;
    float c = 0.f;
    #pragma unroll 8
    for (int d=0; d<32; ++d) c = fmaf(W[hh*32+d], A[hh*32+d], c);
    P2[sel*4 + hh] = c;
  } else if (t == 8){
    int base = 0;
    for (int b=0; b<20; ++b){ bbase[b] = base; base += bsum[b]; }
  } else if (t == 9){
    int base = 0;
    for (int b=20; b<40; ++b){ bbase[b] = base; base += bsum[b]; }
  } else if (t == 10) off_in[NN]  = EE;
  else if   (t == 11) off_trg[NN] = EE;
}

// merged: off[i] write + per-chunk running prefix -> bases[g][chunk][node]
__global__ __launch_bounds__(1024) void k_csrC(const int* __restrict__ histB,
        const int* __restrict__ exc, const int* __restrict__ bbase,
        int* __restrict__ off_in, int* __restrict__ off_trg,
        int* __restrict__ bases){
  int b = blockIdx.x, t = threadIdx.x;      // 40 blocks
  int g = b/20, c2 = b%20;
  int i = c2*1024 + t;
  if (i >= NN) return;
  int* off = g ? off_trg : off_in;
  int running = exc[b*1024 + t] + bbase[b];
  off[i] = running;
  int sh = (i&1)*16;
  for (int cb=0; cb<NCH; ++cb){
    bases[(g*NCH+cb)*NN + i] = running;
    int w = histB[(g*NCH+cb)*(NN/2) + (i>>1)];
    running += (w >> sh) & 0xFFFF;
  }
}

// fill: block = (graph, node-half, chunk); LDS bump allocator (no global atomic returns)
__global__ __launch_bounds__(256) void k_fillL(const int* __restrict__ src_in,
        const int* __restrict__ dst_in, const int* __restrict__ src_trg,
        const int* __restrict__ dst_trg, const int* __restrict__ bases,
        ushortT* __restrict__ csr_in, ushortT* __restrict__ csr_trg){
  int b = blockIdx.x;                  // 0..319
  int g = b / (2*NCH);
  int rem = b % (2*NCH);
  int half = rem / NCH, c = rem % NCH;
  const int* src = g ? src_trg : src_in;
  const int* dst = g ? dst_trg : dst_in;
  ushortT* csr = g ? csr_trg : csr_in;
  __shared__ int alloc[NN/2];
  const int* basep = bases + (g*NCH+c)*NN + half*(NN/2);
  for (int i=threadIdx.x; i<NN/2; i+=256) alloc[i] = basep[i];
  __syncthreads();
  int e0 = c*CHE;
  int lo = half*(NN/2);
  for (int k=threadIdx.x; k<CHE; k+=256){
    int d = dst[e0+k];
    int dl = d - lo;
    if ((unsigned)dl < (unsigned)(NN/2)){
      int p = atomicAdd(&alloc[dl], 1);
      csr[p] = (ushortT)src[e0+k];
    }
  }
}

// ---------------- fused feat+el/er; feat stored BF16 TRANSPOSED [h][NN][32].
// GRID-STRIDE (R16): stage W once per block, loop node-chunks — 10x fewer
// blocks and 10x less redundant weight traffic than one-chunk-per-block.
template<int IN, int OUT, int H>
__global__ __launch_bounds__(256) void k_featel(const float* __restrict__ z,
        const float* __restrict__ W, const float* __restrict__ AL,
        const float* __restrict__ AR, ushortT* __restrict__ featb,
        float* __restrict__ el, float* __restrict__ er){
  __shared__ float Ws[IN*(OUT+1)];
  __shared__ float ALs[OUT], ARs[OUT];
  for (int idx=threadIdx.x; idx<IN*OUT; idx+=256){
    int o = idx / IN, i = idx % IN;
    Ws[i*(OUT+1) + o] = W[idx];
  }
  for (int idx=threadIdx.x; idx<OUT; idx+=256){ ALs[idx]=AL[idx]; ARs[idx]=AR[idx]; }
  __syncthreads();
  const int NCHK = (NN*OUT)/256;       // exact multiple
  for (int chunk = blockIdx.x; chunk < NCHK; chunk += gridDim.x){
    int tid = chunk*256 + threadIdx.x;
    int n = tid / OUT, o = tid % OUT;
    const float4* z4 = (const float4*)(z + n*IN);
    float acc = 0.f;
    #pragma unroll
    for (int i=0;i<IN/4;++i){
      float4 zv = z4[i];
      acc = fmaf(zv.x, Ws[(4*i+0)*(OUT+1)+o], acc);
      acc = fmaf(zv.y, Ws[(4*i+1)*(OUT+1)+o], acc);
      acc = fmaf(zv.z, Ws[(4*i+2)*(OUT+1)+o], acc);
      acc = fmaf(zv.w, Ws[(4*i+3)*(OUT+1)+o], acc);
    }
    int h = o >> 5, d = o & 31;
    featb[(h*NN + n)*32 + d] = f2bf(acc);
    float a = acc * ALs[o], b = acc * ARs[o];
    #pragma unroll
    for (int msk=1; msk<32; msk<<=1){
      a += __shfl_xor(a, msk);
      b += __shfl_xor(b, msk);
    }
    if (d == 0){
      el[h*NN + n] = a;
      er[h*NN + n] = b;
    }
  }
}

// ---------------- layer 1 fused (IN=1 algebraic collapse) — f32 path, unchanged
__global__ __launch_bounds__(256) void k_l1(const int* __restrict__ off,
        const ushortT* __restrict__ csr, const float* __restrict__ X,
        const float* __restrict__ P, const float* __restrict__ P2,
        float* __restrict__ out){
  int wv = threadIdx.x >> 6, l = threadIdx.x & 63;
  int n = blockIdx.x*4 + wv;
  if (n >= NN) return;
  int start = off[n], deg = off[n+1] - start;
  int hl = l & 3, jl = l >> 2;
  float cl = P2[hl], cr = P2[4 + hl];
  float xd = X[n];
  float m = -INFINITY, ssum = 0.f, t = 0.f;
  for (int j = jl; j < deg; j += 16){
    int s = csr[start + j];
    float xs = X[s];
    float e = lrelu(xs*cl + xd*cr);
    if (e > m){
      float w = __expf(m - e);
      ssum = ssum*w + 1.f;
      t    = t*w + xs;
      m = e;
    } else {
      float w = __expf(e - m);
      ssum += w;
      t    = fmaf(w, xs, t);
    }
  }
  #pragma unroll
  for (int msk=4; msk<64; msk<<=1){
    float mo = __shfl_xor(m, msk), so = __shfl_xor(ssum, msk), to = __shfl_xor(t, msk);
    float mn = fmaxf(m, mo);
    if (mn > -INFINITY){
      float w1 = __expf(m - mn), w2 = __expf(mo - mn);
      ssum = ssum*w1 + so*w2;
      t    = t*w1 + to*w2;
    }
    m = mn;
  }
  float tv = t / (ssum + 1e-9f);
  float th = __shfl(tv, l >> 4);
  const float2 w2v = *(const float2*)(P + 2*l);
  const float2 b2v = *(const float2*)(P + 128 + 2*l);
  float2 o;
  o.x = fmaf(th, w2v.x, b2v.x);
  o.y = fmaf(th, w2v.y, b2v.y);
  *(float2*)(out + n*128 + 2*l) = o;
}

// ---------------- aggregation (EXACT R13 form — empirically best):
// wave per (node, head), phase-major grid; bf16 feat planes [h][NN][32];
// fast path deg<=64 (plain max->exp, no rescale); (alpha,src) staged in LDS;
// PV = 8 edge-groups x 8 lanes x uint2; asum rides the group reduce.
// All shfl/LDS loops keep wave-uniform trip counts (R5 lesson).
// (R14 lesson: merged-head wave kills TLP; R15 lesson: 16x4xuint4 widening
//  regresses — keep 8x8xuint2.)
template<int H, bool ELU>
__global__ __launch_bounds__(256) void k_aggH(const int* __restrict__ off,
        const ushortT* __restrict__ csr, const ushortT* __restrict__ featb,
        const float* __restrict__ el, const float* __restrict__ er,
        const float* __restrict__ bias, float* __restrict__ out){
  __shared__ float2 as_[4][64];
  int wv = threadIdx.x >> 6, l = threadIdx.x & 63;
  int bid = blockIdx.x;
  int h = bid / NB4C, b = bid % NB4C;
  int n = b*4 + wv;
  if (n >= NN) return;
  const float* elh = el + h*NN;
  const ushortT* fh = featb + (size_t)h*NN*32;
  int start = off[n], deg = off[n+1] - start;
  float erl = er[h*NN + n];
  int g = l >> 3, dl = l & 7;   // 8 edge-groups x 8 lanes; uint2 (4 bf16) per lane
  float4 acc = make_float4(0.f, 0.f, 0.f, 0.f);
  float asum = 0.f;
  if (deg <= 64){
    int s = 0; float e = -INFINITY;
    if (l < deg){ s = csr[start + l]; e = lrelu(elh[s] + erl); }
    float m = e;
    #pragma unroll
    for (int msk=1; msk<64; msk<<=1) m = fmaxf(m, __shfl_xor(m, msk));
    float a = (l < deg) ? __expf(e - m) : 0.f;
    as_[wv][l] = make_float2(a, __int_as_float(s));
    #pragma unroll 4
    for (int jj = 0; jj < deg; jj += 8){       // uniform trip count
      float2 pr = as_[wv][jj + g];             // jj+g <= 56+7 = 63
      float aj = pr.x; int sj = __float_as_int(pr.y);
      uint2 w = *(const uint2*)(fh + sj*32 + 4*dl);
      acc.x = fmaf(aj, bfl(w.x), acc.x);
      acc.y = fmaf(aj, bfh(w.x), acc.y);
      acc.z = fmaf(aj, bfl(w.y), acc.z);
      acc.w = fmaf(aj, bfh(w.y), acc.w);
      asum += aj;
    }
  } else {
    float m = -INFINITY;
    for (int j0 = 0; j0 < deg; j0 += 64){
      int j = j0 + l;
      int s = 0; float e = -INFINITY;
      if (j < deg){ s = csr[start + j]; e = lrelu(elh[s] + erl); }
      float cm = e;
      #pragma unroll
      for (int msk=1; msk<64; msk<<=1) cm = fmaxf(cm, __shfl_xor(cm, msk));
      float mn = fmaxf(m, cm);
      float rs = __expf(m - mn);     // 0 on first chunk (m=-inf), acc/asum are 0
      float a = (j < deg) ? __expf(e - mn) : 0.f;
      acc.x *= rs; acc.y *= rs; acc.z *= rs; acc.w *= rs;
      asum *= rs;
      m = mn;
      as_[wv][l] = make_float2(a, __int_as_float(s));
      int cnt = deg - j0; if (cnt > 64) cnt = 64;
      #pragma unroll 4
      for (int jj = 0; jj < cnt; jj += 8){
        float2 pr = as_[wv][jj + g];
        float aj = pr.x; int sj = __float_as_int(pr.y);
        uint2 w = *(const uint2*)(fh + sj*32 + 4*dl);
        acc.x = fmaf(aj, bfl(w.x), acc.x);
        acc.y = fmaf(aj, bfh(w.x), acc.y);
        acc.z = fmaf(aj, bfl(w.y), acc.z);
        acc.w = fmaf(aj, bfh(w.y), acc.w);
        asum += aj;
      }
    }
  }
  #pragma unroll
  for (int msk=8; msk<64; msk<<=1){
    acc.x += __shfl_xor(acc.x, msk);
    acc.y += __shfl_xor(acc.y, msk);
    acc.z += __shfl_xor(acc.z, msk);
    acc.w += __shfl_xor(acc.w, msk);
    asum  += __shfl_xor(asum,  msk);
  }
  float sinv = 1.f/(asum + 1e-9f);
  if (l < 8){
    const float4 b4 = *(const float4*)(bias + h*32 + 4*l);
    float o0 = fmaf(acc.x, sinv, b4.x);
    float o1 = fmaf(acc.y, sinv, b4.y);
    float o2 = fmaf(acc.z, sinv, b4.z);
    float o3 = fmaf(acc.w, sinv, b4.w);
    if (ELU){
      o0 = o0 > 0.f ? o0 : expm1f(o0);
      o1 = o1 > 0.f ? o1 : expm1f(o1);
      o2 = o2 > 0.f ? o2 : expm1f(o2);
      o3 = o3 > 0.f ? o3 : expm1f(o3);
    }
    *(float4*)(out + n*(H*32) + h*32 + 4*l) = make_float4(o0, o1, o2, o3);
  }
}

// ---------------- workspace layout (float elements) — ALL live buffers 512B-aligned
#define WS_P     0
#define WS_P2    22144
#define WS_EL    22272
#define WS_ER    102272
#define WS_FEAT  262144      // bf16 [h][NN][32], max 4*NN*32*2B
#define WS_ZA    2822144
#define WS_ZB    5382144
#define WS_OFFI  6022144
#define WS_OFFT  6042240
#define WS_CSRI  6423552
#define WS_CSRT  6743552
#define WS_TOTAL 7063552     // 28.25 MB (unchanged)
// CSR-build scratch ALIASED into feat+zA region (dead until k_l1 / layer 2):
#define WS_HB    (WS_FEAT + 0)        // histB: 160 * 10000 ints
#define WS_BS    (WS_FEAT + 1600000)  // bases: 160 * 20000 ints
#define WS_EXC   (WS_FEAT + 4800000)  // 40*1024 ints
#define WS_BSUM  (WS_FEAT + 4841472)  // 40 ints
#define WS_BBASE (WS_FEAT + 4841600)  // 40 ints

extern "C" void kernel_launch(void* const* d_in, const int* in_sizes, int n_in,
                              void* d_out, int out_size, void* d_ws, size_t ws_size,
                              hipStream_t stream) {
  if (ws_size < (size_t)WS_TOTAL * sizeof(float)) {
    hipMemsetAsync(d_out, 0, (size_t)out_size * sizeof(float), stream);
    return;
  }
  const float* X      = (const float*)d_in[0];
  const float* m1     = (const float*)d_in[1];
  const float* mt     = (const float*)d_in[2];
  const float* Whin   = (const float*)d_in[3];
  const float* bhin   = (const float*)d_in[4];
  const float* Whout  = (const float*)d_in[5];
  const float* bhout  = (const float*)d_in[6];
  const int* src_in   = (const int*)d_in[7];
  const int* dst_in   = (const int*)d_in[8];
  const int* src_trg  = (const int*)d_in[9];
  const int* dst_trg  = (const int*)d_in[10];
  float* out = (float*)d_out;
  float* ws  = (float*)d_ws;

  float* P    = ws + WS_P;
  float* P2   = ws + WS_P2;
  float* el   = ws + WS_EL;
  float* er   = ws + WS_ER;
  ushortT* featb = (ushortT*)(ws + WS_FEAT);
  float* zA   = ws + WS_ZA;
  float* zB   = ws + WS_ZB;
  int* off_in  = (int*)(ws + WS_OFFI);
  int* off_trg = (int*)(ws + WS_OFFT);
  int* histB   = (int*)(ws + WS_HB);
  int* bases   = (int*)(ws + WS_BS);
  int* exc     = (int*)(ws + WS_EXC);
  int* bsum    = (int*)(ws + WS_BSUM);
  int* bbase   = (int*)(ws + WS_BBASE);
  ushortT* csr_in  = (ushortT*)(ws + WS_CSRI);
  ushortT* csr_trg = (ushortT*)(ws + WS_CSRT);

  // params + histograms (fused, independent block ranges)
  k_prmhist<<<2*NCH + 87, 256, 0, stream>>>(m1, mt, Whin, bhin, Whout, bhout, P,
                                            dst_in, dst_trg, histB);
  k_csrA<<<40, 1024, 0, stream>>>(histB, exc, bsum);
  k_csrB<<<1, 64, 0, stream>>>(bsum, bbase, off_in, off_trg, P, P2);
  k_csrC<<<40, 1024, 0, stream>>>(histB, exc, bbase, off_in, off_trg, bases);
  k_fillL<<<4*NCH, 256, 0, stream>>>(src_in, dst_in, src_trg, dst_trg, bases,
                                     csr_in, csr_trg);

  // Layer 1: fused (H=4, in=1) -> zA (N x 128)
  k_l1<<<NB4C, 256, 0, stream>>>(off_in, csr_in, X, P, P2, zA);

  // Layer 2: H=1, in=128 -> zB (N x 32), ELU
  k_featel<128,32,1><<<1024, 256, 0, stream>>>(zA, P+512, P+4640, P+4672, featb, el, er);
  k_aggH<1,true><<<NB4C, 256, 0, stream>>>(off_in, csr_in, featb, el, er, P+4608, zB);

  // Layer 3: H=4, in=32 -> zA (N x 128)
  k_featel<32,128,4><<<1024, 256, 0, stream>>>(zB, P+4704, P+8928, P+9056, featb, el, er);
  k_aggH<4,false><<<4*NB4C, 256, 0, stream>>>(off_trg, csr_trg, featb, el, er, P+8800, zA);

  // Layer 4: H=1, in=128 -> zB (N x 32), ELU
  k_featel<128,32,1><<<1024, 256, 0, stream>>>(zA, P+9184, P+13312, P+13344, featb, el, er);
  k_aggH<1,true><<<NB4C, 256, 0, stream>>>(off_trg, csr_trg, featb, el, er, P+13280, zB);

  // Layer 5: H=4, in=32 -> zA (N x 128)
  k_featel<32,128,4><<<1024, 256, 0, stream>>>(zB, P+13376, P+17600, P+17728, featb, el, er);
  k_aggH<4,false><<<4*NB4C, 256, 0, stream>>>(off_trg, csr_trg, featb, el, er, P+17472, zA);

  // Layer 6: H=1, in=128 -> out (N x 32), ELU
  k_featel<128,32,1><<<1024, 256, 0, stream>>>(zA, P+17856, P+21984, P+22016, featb, el, er);
  k_aggH<1,true><<<NB4C, 256, 0, stream>>>(off_trg, csr_trg, featb, el, er, P+21952, out);
}